// Round 5
// baseline (80.433 us; speedup 1.0000x reference)
//
#include <hip/hip_runtime.h>
#include <hip/hip_bf16.h>

#define BB 16
#define SS 512
#define HH 1024

typedef __attribute__((ext_vector_type(4))) float f32x4;
typedef __attribute__((ext_vector_type(8))) short bhalf8;

static __device__ __forceinline__ unsigned int pack2(float a, float b) {
    __hip_bfloat162 h = __float22bfloat162_rn(make_float2(a, b));
    union { __hip_bfloat162 h; unsigned int u; } cv;
    cv.h = h;
    return cv.u;
}

// ---------------------------------------------------------------------------
// Prepass: blocks 0..2047: W[e][k][d] f32 -> Wt[e][d][k] bf16 (only for
// experts actually selected); blocks 2048..2063: zero the row-sum buffer.
// ---------------------------------------------------------------------------
__global__ __launch_bounds__(256)
void prep_kernel(const float* __restrict__ W, const int* __restrict__ eidx,
                 unsigned short* __restrict__ Wt, float* __restrict__ sums)
{
    int bid = blockIdx.x;
    int t = threadIdx.x;
    if (bid < 2048) {
        int e  = bid >> 8;
        bool used = false;
        for (int b = 0; b < BB; ++b) used = used || (eidx[b] == e);
        if (!used) return;
        int rem = bid & 255;
        int kt = rem >> 3, dt = rem & 7;     // 32-k-row x 128-d-col tile
        int kb = t & 7, db = t >> 3;
        const float* src = W + ((size_t)e << 20) + (size_t)(kt * 32 + kb * 4) * HH + dt * 128 + db * 4;
        float4 r0 = *(const float4*)(src);
        float4 r1 = *(const float4*)(src + HH);
        float4 r2 = *(const float4*)(src + 2 * HH);
        float4 r3 = *(const float4*)(src + 3 * HH);
        unsigned short* dst = Wt + ((size_t)e << 20) + (size_t)(dt * 128 + db * 4) * HH + kt * 32 + kb * 4;
#pragma unroll
        for (int c = 0; c < 4; ++c) {
            float c0 = (&r0.x)[c], c1 = (&r1.x)[c], c2 = (&r2.x)[c], c3 = (&r3.x)[c];
            *reinterpret_cast<uint2*>(dst + (size_t)c * HH) =
                make_uint2(pack2(c0, c1), pack2(c2, c3));
        }
    } else {
        int i = (bid - 2048) * 1024 + t * 4;   // 16 blocks cover 16384 floats
        float4 z = {0.f, 0.f, 0.f, 0.f};
        *reinterpret_cast<float4*>(&sums[i]) = z;
    }
}

// ---------------------------------------------------------------------------
// GEMM (+bias+residual): 512 blocks x 256 thr (4 waves, 2m x 2n, wave 64x64),
// 128x128 tile, BK=32, double-buffered LDS (48KB -> 3 blocks/CU),
// global_load_lds width-16 for both operands, plain __syncthreads (m97 shape).
// A: f32 in LDS, rows 128B, phys slot = s ^ (r&7); cvt to bf16 on read.
// W: bf16 in LDS, 2 d-rows per 128B line, phys pos = (s + 4(d&1)) ^ (line&7).
// mfma 16x16x32 bf16: 16/wave/step vs 12 ds_read_b128/wave/step.
// ---------------------------------------------------------------------------
__global__ __launch_bounds__(256, 2)
void moe_gemm_kernel(const float* __restrict__ hid, const float* __restrict__ inp,
                     const int* __restrict__ eidx, const unsigned short* __restrict__ Wt,
                     const float* __restrict__ bias, float* __restrict__ sums,
                     float* __restrict__ out)
{
    __shared__ char ldsA[2 * 16384];   // A: f32 [128 r][32 k], swizzled 16B slots
    __shared__ char ldsW[2 * 8192];    // W: bf16 [128 d][32 k], pair-swizzled

    int bx  = blockIdx.x;
    int swz = (bx & 7) * 64 + (bx >> 3);      // XCD-bijective (512 % 8 == 0)
    int bt   = swz >> 5;
    int tile = swz & 31;
    int mt = tile >> 3, nt = tile & 7;
    int e = eidx[bt];

    int t = threadIdx.x, wave = t >> 6, lane = t & 63;
    int l15 = lane & 15, g = lane >> 4;       // g in 0..3
    int wm = wave >> 1, wn = wave & 1;        // 2x2 wave grid, 64x64 each

    // ---- staging descriptors ----
    // A: 1024 chunks of 16B (4/thread). phys chunk c: r=c>>3, p=c&7, s=p^(r&7)
    const float* asrc[4];
    int aoff[4];
#pragma unroll
    for (int i = 0; i < 4; ++i) {
        int c = t + i * 256;
        int r = c >> 3, p = c & 7, s = p ^ (r & 7);
        asrc[i] = hid + (size_t)(bt * SS + mt * 128 + r) * HH + s * 4;
        aoff[i] = c * 16;
    }
    // W: 512 chunks of 16B (2/thread). phys c: line=c>>3, p=c&7, q=p^(line&7),
    // d = line*2 + (q>>2), s = q&3.
    const unsigned short* wsrc[2];
    int woff[2];
#pragma unroll
    for (int i = 0; i < 2; ++i) {
        int c = t + i * 256;
        int line = c >> 3, p = c & 7, q = p ^ (line & 7);
        int d = line * 2 + (q >> 2), s = q & 3;
        wsrc[i] = Wt + ((size_t)e << 20) + (size_t)(nt * 128 + d) * HH + s * 8;
        woff[i] = c * 16;
    }

    auto stage = [&](int ks, int sel) {
#pragma unroll
        for (int i = 0; i < 4; ++i)
            __builtin_amdgcn_global_load_lds(
                (const __attribute__((address_space(1))) void*)(asrc[i] + ks * 32),
                (__attribute__((address_space(3))) void*)(ldsA + sel * 16384 + aoff[i]),
                16, 0, 0);
#pragma unroll
        for (int i = 0; i < 2; ++i)
            __builtin_amdgcn_global_load_lds(
                (const __attribute__((address_space(1))) void*)(wsrc[i] + ks * 32),
                (__attribute__((address_space(3))) void*)(ldsW + sel * 8192 + woff[i]),
                16, 0, 0);
    };

    f32x4 acc[4][4] = {};

    stage(0, 0);
    __syncthreads();

    for (int ks = 0; ks < 32; ++ks) {
        int sel = ks & 1;
        if (ks < 31) stage(ks + 1, sel ^ 1);

        const char* Af = ldsA + sel * 16384;
        const char* Wf = ldsW + sel * 8192;

        bhalf8 af[4], bf[4];
#pragma unroll
        for (int mf = 0; mf < 4; ++mf) {
            int r = wm * 64 + mf * 16 + l15;
            const char* base = Af + r * 128;
            f32x4 f0 = *(const f32x4*)(base + (((2 * g)     ^ (r & 7)) << 4));
            f32x4 f1 = *(const f32x4*)(base + (((2 * g + 1) ^ (r & 7)) << 4));
            union { unsigned int u[4]; bhalf8 h; } cv;
            cv.u[0] = pack2(f0[0], f0[1]); cv.u[1] = pack2(f0[2], f0[3]);
            cv.u[2] = pack2(f1[0], f1[1]); cv.u[3] = pack2(f1[2], f1[3]);
            af[mf] = cv.h;
        }
#pragma unroll
        for (int nf = 0; nf < 4; ++nf) {
            int d = wn * 64 + nf * 16 + l15;
            int line = d >> 1;
            int p = (g + ((d & 1) << 2)) ^ (line & 7);
            bf[nf] = *(const bhalf8*)(Wf + line * 128 + p * 16);
        }
#pragma unroll
        for (int mf = 0; mf < 4; ++mf)
#pragma unroll
            for (int nf = 0; nf < 4; ++nf)
                acc[mf][nf] = __builtin_amdgcn_mfma_f32_16x16x32_bf16(
                    af[mf], bf[nf], acc[mf][nf], 0, 0, 0);
        __syncthreads();
    }

    // ---- epilogue: x = acc + bias + inp; write x to out ----
    int brow = bt * SS + mt * 128;
#pragma unroll
    for (int nf = 0; nf < 4; ++nf) {
        int dcol = nt * 128 + wn * 64 + nf * 16 + l15;
        float bv = bias[e * HH + dcol];
#pragma unroll
        for (int mf = 0; mf < 4; ++mf)
#pragma unroll
            for (int j = 0; j < 4; ++j) {
                int srow = brow + wm * 64 + mf * 16 + g * 4 + j;
                size_t off = (size_t)srow * HH + dcol;
                float v = acc[mf][nf][j] + bv + inp[off];
                acc[mf][nf][j] = v;
                out[off] = v;
            }
    }

    // ---- per-row partial sums (16-lane shuffle reduce) + atomics ----
#pragma unroll
    for (int mf = 0; mf < 4; ++mf)
#pragma unroll
        for (int j = 0; j < 4; ++j) {
            float s1 = 0.f, s2 = 0.f;
#pragma unroll
            for (int nf = 0; nf < 4; ++nf) {
                float v = acc[mf][nf][j];
                s1 += v; s2 += v * v;
            }
#pragma unroll
            for (int m = 8; m >= 1; m >>= 1) {
                s1 += __shfl_xor(s1, m, 64);
                s2 += __shfl_xor(s2, m, 64);
            }
            if (l15 == 0) {
                int r = brow + wm * 64 + mf * 16 + g * 4 + j;
                atomicAdd(&sums[r * 2], s1);
                atomicAdd(&sums[r * 2 + 1], s2);
            }
        }
}

// ---------------------------------------------------------------------------
// LN apply: one block per row; row chosen so block's XCD matches the gemm
// block that wrote it (x row-panel bt lives on XCD bt>>1) -> L2-hit reads.
// ---------------------------------------------------------------------------
__global__ __launch_bounds__(256)
void ln_apply(float* __restrict__ x, const float* __restrict__ sums,
              const float* __restrict__ gamma, const float* __restrict__ beta)
{
    int bid = blockIdx.x;
    int row = ((bid & 7) << 10) | (bid >> 3);   // XCD-matched permutation
    int t = threadIdx.x;
    float s1 = sums[row * 2], s2 = sums[row * 2 + 1];
    float mu  = s1 * (1.0f / HH);
    float var = s2 * (1.0f / HH) - mu * mu;
    float rs = rsqrtf(var + 1e-12f);
    size_t base = (size_t)row * HH + t * 4;
    float4 v  = *reinterpret_cast<const float4*>(&x[base]);
    float4 gv = *reinterpret_cast<const float4*>(&gamma[t * 4]);
    float4 bv = *reinterpret_cast<const float4*>(&beta[t * 4]);
    float4 o;
    o.x = (v.x - mu) * rs * gv.x + bv.x;
    o.y = (v.y - mu) * rs * gv.y + bv.y;
    o.z = (v.z - mu) * rs * gv.z + bv.z;
    o.w = (v.w - mu) * rs * gv.w + bv.w;
    *reinterpret_cast<float4*>(&x[base]) = o;
}

extern "C" void kernel_launch(void* const* d_in, const int* in_sizes, int n_in,
                              void* d_out, int out_size, void* d_ws, size_t ws_size,
                              hipStream_t stream) {
    const float* hid   = (const float*)d_in[0];
    const float* inp   = (const float*)d_in[1];
    const int*   eidx  = (const int*)d_in[2];
    const float* W     = (const float*)d_in[3];
    const float* bias  = (const float*)d_in[4];
    const float* gamma = (const float*)d_in[5];
    const float* beta  = (const float*)d_in[6];
    float* out = (float*)d_out;

    unsigned short* Wt = (unsigned short*)d_ws;            // 16 MiB bf16 [8][1024][1024] (d-major)
    float* sums = (float*)((char*)d_ws + (16u << 20));     // 8192 rows x {S1,S2}

    prep_kernel<<<2064, 256, 0, stream>>>(W, eidx, Wt, sums);
    moe_gemm_kernel<<<512, 256, 0, stream>>>(hid, inp, eidx, Wt, bias, sums, out);
    ln_apply<<<BB * SS, 256, 0, stream>>>(out, sums, gamma, beta);
}

// Round 6
// 77.169 us; speedup vs baseline: 1.0423x; 1.0423x over previous
//
#include <hip/hip_runtime.h>
#include <hip/hip_bf16.h>

#define BB 16
#define SS 512
#define HH 1024

typedef __attribute__((ext_vector_type(4))) float f32x4;
typedef __attribute__((ext_vector_type(8))) short bhalf8;

static __device__ __forceinline__ unsigned int pack2(float a, float b) {
    __hip_bfloat162 h = __float22bfloat162_rn(make_float2(a, b));
    union { __hip_bfloat162 h; unsigned int u; } cv;
    cv.h = h;
    return cv.u;
}

// ---------------------------------------------------------------------------
// Prepass: blocks 0..2047: W[e][k][d] f32 -> Wt[e][d][k] bf16 (only for
// experts actually selected); blocks 2048..2063: zero the row-sum buffer.
// ---------------------------------------------------------------------------
__global__ __launch_bounds__(256)
void prep_kernel(const float* __restrict__ W, const int* __restrict__ eidx,
                 unsigned short* __restrict__ Wt, float* __restrict__ sums)
{
    int bid = blockIdx.x;
    int t = threadIdx.x;
    if (bid < 2048) {
        int e  = bid >> 8;
        bool used = false;
        for (int b = 0; b < BB; ++b) used = used || (eidx[b] == e);
        if (!used) return;
        int rem = bid & 255;
        int kt = rem >> 3, dt = rem & 7;     // 32-k-row x 128-d-col tile
        int kb = t & 7, db = t >> 3;
        const float* src = W + ((size_t)e << 20) + (size_t)(kt * 32 + kb * 4) * HH + dt * 128 + db * 4;
        float4 r0 = *(const float4*)(src);
        float4 r1 = *(const float4*)(src + HH);
        float4 r2 = *(const float4*)(src + 2 * HH);
        float4 r3 = *(const float4*)(src + 3 * HH);
        unsigned short* dst = Wt + ((size_t)e << 20) + (size_t)(dt * 128 + db * 4) * HH + kt * 32 + kb * 4;
#pragma unroll
        for (int c = 0; c < 4; ++c) {
            float c0 = (&r0.x)[c], c1 = (&r1.x)[c], c2 = (&r2.x)[c], c3 = (&r3.x)[c];
            *reinterpret_cast<uint2*>(dst + (size_t)c * HH) =
                make_uint2(pack2(c0, c1), pack2(c2, c3));
        }
    } else {
        int i = (bid - 2048) * 1024 + t * 4;   // 16 blocks cover 16384 floats
        float4 z = {0.f, 0.f, 0.f, 0.f};
        *reinterpret_cast<float4*>(&sums[i]) = z;
    }
}

// ---------------------------------------------------------------------------
// GEMM (+bias+residual): 1024 blocks x 256 thr -> 4 resident blocks/CU.
// Tile 64x128, 4 waves (2m x 2n, wave 32x64), BK=32, dbuf LDS 24KB.
// A: reg-staged f32->bf16 (cvt at write time); W: global_load_lds from Wt.
// LDS rows 64B -> b128 frag reads are bank-floor (no swizzle needed).
// ONE barrier per K-iter. mfma 16x16x32 bf16, 8/wave/iter.
// ---------------------------------------------------------------------------
__global__ __launch_bounds__(256, 4)
void moe_gemm_kernel(const float* __restrict__ hid, const float* __restrict__ inp,
                     const int* __restrict__ eidx, const unsigned short* __restrict__ Wt,
                     const float* __restrict__ bias, float* __restrict__ sums,
                     float* __restrict__ out)
{
    __shared__ char ldsA[2 * 4096];    // A: bf16 [64 r][32 k], rows 64B
    __shared__ char ldsW[2 * 8192];    // W: bf16 [128 d][32 k], rows 64B

    int bid = blockIdx.x;
    int swz = (bid & 7) * 128 + (bid >> 3);   // XCD x -> 2 contiguous batches
    int bt  = swz >> 6;
    int rem = swz & 63;
    int mt = rem >> 3, nt = rem & 7;          // 8 m-tiles x 8 n-tiles
    int e = eidx[bt];

    int t = threadIdx.x, wave = t >> 6, lane = t & 63;
    int l15 = lane & 15, g = lane >> 4;       // g in 0..3
    int wm = wave >> 1, wn = wave & 1;        // wave tile 32 x 64

    int brow = bt * SS + mt * 64;

    // A staging: thread -> row = t>>2 (0..63), slot = t&3 (8 k each)
    int arow = t >> 2, aslot = t & 3;
    const float* asrc = hid + (size_t)(brow + arow) * HH + aslot * 8;
    char* adst = ldsA + arow * 64 + aslot * 16;

    // W staging: chunks c = t, t+256: d = c>>2, slot = c&3 (8 k each)
    const unsigned short* wsrc[2];
    int woff[2];
#pragma unroll
    for (int i = 0; i < 2; ++i) {
        int c = t + i * 256;
        wsrc[i] = Wt + ((size_t)e << 20) + (size_t)(nt * 128 + (c >> 2)) * HH + (c & 3) * 8;
        woff[i] = c * 16;
    }

    auto stageW = [&](int ks, int sel) {
#pragma unroll
        for (int i = 0; i < 2; ++i)
            __builtin_amdgcn_global_load_lds(
                (const __attribute__((address_space(1))) void*)(wsrc[i] + ks * 32),
                (__attribute__((address_space(3))) void*)(ldsW + sel * 8192 + woff[i]),
                16, 0, 0);
    };

    float4 a0, a1;
    auto loadA = [&](int ks) {
        a0 = *reinterpret_cast<const float4*>(asrc + ks * 32);
        a1 = *reinterpret_cast<const float4*>(asrc + ks * 32 + 4);
    };
    auto writeA = [&](int sel) {
        union { unsigned int u[4]; } cv;
        cv.u[0] = pack2(a0.x, a0.y); cv.u[1] = pack2(a0.z, a0.w);
        cv.u[2] = pack2(a1.x, a1.y); cv.u[3] = pack2(a1.z, a1.w);
        *reinterpret_cast<uint4*>(adst + sel * 4096) = make_uint4(cv.u[0], cv.u[1], cv.u[2], cv.u[3]);
    };

    f32x4 acc[2][4] = {};

    // prologue: buf0 = tile 0; regs = A(1)
    loadA(0);
    stageW(0, 0);
    writeA(0);
    loadA(1);
    __syncthreads();

    for (int ks = 0; ks < 32; ++ks) {
        int sel = ks & 1;
        // stage next tile into buf[sel^1] while computing buf[sel]
        if (ks < 31) {
            writeA(sel ^ 1);          // A(ks+1) from regs
            stageW(ks + 1, sel ^ 1);
        }
        if (ks < 30) loadA(ks + 2);   // refill regs (hidden under MFMA)

        bhalf8 af[2], bf[4];
#pragma unroll
        for (int mf = 0; mf < 2; ++mf)
            af[mf] = *reinterpret_cast<const bhalf8*>(
                ldsA + sel * 4096 + (wm * 32 + mf * 16 + l15) * 64 + g * 16);
#pragma unroll
        for (int nf = 0; nf < 4; ++nf)
            bf[nf] = *reinterpret_cast<const bhalf8*>(
                ldsW + sel * 8192 + (wn * 64 + nf * 16 + l15) * 64 + g * 16);
#pragma unroll
        for (int mf = 0; mf < 2; ++mf)
#pragma unroll
            for (int nf = 0; nf < 4; ++nf)
                acc[mf][nf] = __builtin_amdgcn_mfma_f32_16x16x32_bf16(
                    af[mf], bf[nf], acc[mf][nf], 0, 0, 0);
        __syncthreads();
    }

    // ---- epilogue: x = acc + bias + inp; write x to out ----
#pragma unroll
    for (int nf = 0; nf < 4; ++nf) {
        int dcol = nt * 128 + wn * 64 + nf * 16 + l15;
        float bv = bias[e * HH + dcol];
#pragma unroll
        for (int mf = 0; mf < 2; ++mf)
#pragma unroll
            for (int j = 0; j < 4; ++j) {
                int srow = brow + wm * 32 + mf * 16 + g * 4 + j;
                size_t off = (size_t)srow * HH + dcol;
                float v = acc[mf][nf][j] + bv + inp[off];
                acc[mf][nf][j] = v;
                out[off] = v;
            }
    }

    // ---- per-row partial sums (16-lane shuffle reduce) + atomics ----
#pragma unroll
    for (int mf = 0; mf < 2; ++mf)
#pragma unroll
        for (int j = 0; j < 4; ++j) {
            float s1 = 0.f, s2 = 0.f;
#pragma unroll
            for (int nf = 0; nf < 4; ++nf) {
                float v = acc[mf][nf][j];
                s1 += v; s2 += v * v;
            }
#pragma unroll
            for (int m = 8; m >= 1; m >>= 1) {
                s1 += __shfl_xor(s1, m, 64);
                s2 += __shfl_xor(s2, m, 64);
            }
            if (l15 == 0) {
                int r = brow + wm * 32 + mf * 16 + g * 4 + j;
                atomicAdd(&sums[r * 2], s1);
                atomicAdd(&sums[r * 2 + 1], s2);
            }
        }
}

// ---------------------------------------------------------------------------
// LN apply: one block per row; XCD-matched row permutation so reads hit the
// L2 of the XCD whose gemm blocks wrote that row-panel.
// ---------------------------------------------------------------------------
__global__ __launch_bounds__(256)
void ln_apply(float* __restrict__ x, const float* __restrict__ sums,
              const float* __restrict__ gamma, const float* __restrict__ beta)
{
    int bid = blockIdx.x;
    int row = ((bid & 7) << 10) | (bid >> 3);
    int t = threadIdx.x;
    float s1 = sums[row * 2], s2 = sums[row * 2 + 1];
    float mu  = s1 * (1.0f / HH);
    float var = s2 * (1.0f / HH) - mu * mu;
    float rs = rsqrtf(var + 1e-12f);
    size_t base = (size_t)row * HH + t * 4;
    float4 v  = *reinterpret_cast<const float4*>(&x[base]);
    float4 gv = *reinterpret_cast<const float4*>(&gamma[t * 4]);
    float4 bv = *reinterpret_cast<const float4*>(&beta[t * 4]);
    float4 o;
    o.x = (v.x - mu) * rs * gv.x + bv.x;
    o.y = (v.y - mu) * rs * gv.y + bv.y;
    o.z = (v.z - mu) * rs * gv.z + bv.z;
    o.w = (v.w - mu) * rs * gv.w + bv.w;
    *reinterpret_cast<float4*>(&x[base]) = o;
}

extern "C" void kernel_launch(void* const* d_in, const int* in_sizes, int n_in,
                              void* d_out, int out_size, void* d_ws, size_t ws_size,
                              hipStream_t stream) {
    const float* hid   = (const float*)d_in[0];
    const float* inp   = (const float*)d_in[1];
    const int*   eidx  = (const int*)d_in[2];
    const float* W     = (const float*)d_in[3];
    const float* bias  = (const float*)d_in[4];
    const float* gamma = (const float*)d_in[5];
    const float* beta  = (const float*)d_in[6];
    float* out = (float*)d_out;

    unsigned short* Wt = (unsigned short*)d_ws;            // 16 MiB bf16 [8][1024][1024] (d-major)
    float* sums = (float*)((char*)d_ws + (16u << 20));     // 8192 rows x {S1,S2}

    prep_kernel<<<2064, 256, 0, stream>>>(W, eidx, Wt, sums);
    moe_gemm_kernel<<<1024, 256, 0, stream>>>(hid, inp, eidx, Wt, bias, sums, out);
    ln_apply<<<BB * SS, 256, 0, stream>>>(out, sums, gamma, beta);
}